// Round 10
// baseline (520.993 us; speedup 1.0000x reference)
//
#include <hip/hip_runtime.h>
#include <cstddef>

#define H_ 256
#define W_ 256
#define HW_ 65536

typedef unsigned int uint;
typedef unsigned short ushort;
typedef __attribute__((ext_vector_type(8))) short short8;
typedef __attribute__((ext_vector_type(16))) float floatx16;

__device__ __forceinline__ float bf2f(ushort u) {
    return __uint_as_float(((uint)u) << 16);
}
__device__ __forceinline__ ushort f2bf(float f) {
    uint u = __float_as_uint(f);
    uint r = (u + 0x7fffu + ((u >> 16) & 1u)) >> 16;
    return (ushort)r;
}
__device__ __forceinline__ float sigmoidf_(float x) {
    return 1.0f / (1.0f + expf(-x));
}

// ============ weight prep: OIHW fp32 -> MFMA-fragment-ordered bf16 ============
__device__ __forceinline__ void prep_one(const float* src, ushort* dst,
                                         int CO, int CI, int e) {
    int chunk = e / 9216;
    int r = e - chunk * 9216;
    int co = r / 288;
    int kk = r - co * 288;
    int khw = kk >> 5;
    int ci = kk & 31;
    int cig = chunk * 32 + ci;
    float v = 0.f;
    if (co < CO && cig < CI) v = src[(co * CI + cig) * 9 + khw];
    int s = kk >> 4;
    int lane = ((kk >> 3) & 1) * 32 + co;
    int j = kk & 7;
    dst[(((size_t)chunk * 18 + s) * 64 + lane) * 8 + j] = f2bf(v);
}

__global__ __launch_bounds__(256) void prep_weights(
    const float* __restrict__ w_in, const float* __restrict__ w2,
    const float* __restrict__ w3, const float* __restrict__ aw1,
    const float* __restrict__ aw2,
    ushort* __restrict__ w_inB, ushort* __restrict__ w2B,
    ushort* __restrict__ w3B, ushort* __restrict__ aw1B,
    ushort* __restrict__ aw2B, ushort* __restrict__ zp) {
    int idx = blockIdx.x * 256 + threadIdx.x;
    if (idx < 64) zp[idx] = 0;
    if (idx < 9216)        prep_one(w_in, w_inB, 32, 32, idx);
    else if (idx < 46080)  prep_one(w2, w2B, 32, 128, idx - 9216);
    else if (idx < 82944)  prep_one(w3, w3B, 32, 128, idx - 46080);
    else if (idx < 92160)  prep_one(aw1, aw1B, 16, 32, idx - 82944);
    else if (idx < 101376) prep_one(aw2, aw2B, 16, 16, idx - 92160);
}

// ============ x: NCHW fp32 -> NHWC bf16 (32 ch) ============
__global__ __launch_bounds__(256) void transform_x(const float* __restrict__ x,
                                                   ushort* __restrict__ xh) {
    __shared__ float s[64][33];
    const int t = threadIdx.x;
    const int w0 = blockIdx.x * 64, h = blockIdx.y, b = blockIdx.z;
    {
        int ww = t & 63, c0 = (t >> 6) * 8;
#pragma unroll
        for (int j = 0; j < 8; j++) {
            int c = c0 + j;
            s[ww][c] = x[((size_t)(b * 32 + c)) * HW_ + h * W_ + w0 + ww];
        }
    }
    __syncthreads();
    {
        int p = t >> 2, cb = t & 3;
        ushort tmp[8];
#pragma unroll
        for (int j = 0; j < 8; j++) tmp[j] = f2bf(s[p][cb * 8 + j]);
        *(uint4*)(xh + (((size_t)b * HW_ + h * W_ + w0 + p) * 32) + cb * 8) =
            *(const uint4*)tmp;
    }
}

// ============ conv 3x3 implicit GEMM, 128-thread blocks, 4 tiles/wave =========
// Tile 32x8, halo 10x34x4cb (21.25 KB LDS, ~6 blocks/CU for cross-block
// stage/compute overlap). XOR-swizzled slots, conflict-free writes+reads.
// EPI=0: direct bf16 NHWC stores. EPI=1: fused att1x1 -> 4 sigmoid planes.
// EPI=2: fused out1x1 -> fp32 sigmoid out.
template<int NCHUNK, int EPI, bool RELU>
__global__ __launch_bounds__(128, 3) void conv_mfma(
    const ushort* __restrict__ in0, const ushort* __restrict__ in1,
    const ushort* __restrict__ in2, const ushort* __restrict__ in3,
    const ushort* __restrict__ wB, const ushort* __restrict__ zp,
    ushort* __restrict__ outp, const float* __restrict__ aux_w,
    const float* __restrict__ aux_b) {
    __shared__ __align__(16) ushort smem[1360 * 8];  // 21.25 KB
    const int t = threadIdx.x;
    const int wid = t >> 6;          // 2 waves
    const int lane = t & 63;
    const int lco = lane & 31, lhalf = lane >> 5;
    const int w0 = blockIdx.x * 32, h0 = blockIdx.y * 8, b = blockIdx.z;
    const ushort* ins[4] = {in0, in1, in2, in3};

    // staging descriptors: 11 iterations of 128 threads cover 1360 slots
    uint goff[11];
    int slot[11];
    bool ok[11];
#pragma unroll
    for (int i = 0; i < 11; i++) {
        int u = i * 128 + t;
        int row = u / 136;
        int rem = u - row * 136;
        int p = rem >> 2, cb = rem & 3;
        int gh = h0 - 1 + row, gw = w0 - 1 + p;
        ok[i] = (u < 1360) && ((unsigned)gh < 256u) && ((unsigned)gw < 256u);
        goff[i] = ok[i] ? (((uint)b * HW_ + (uint)gh * W_ + (uint)gw) * 32 + cb * 8) : 0u;
        slot[i] = row * 136 + (p << 2) + (cb ^ (p & 3) ^ ((p >> 2) & 3));
    }

    floatx16 acc[4];
#pragma unroll
    for (int q = 0; q < 4; q++)
#pragma unroll
        for (int i = 0; i < 16; i++) acc[q][i] = 0.f;

#pragma unroll
    for (int ch = 0; ch < NCHUNK; ch++) {
        __syncthreads();
        {
            const ushort* inp = ins[ch];
            uint4 v[11];
#pragma unroll
            for (int i = 0; i < 11; i++) {
                const ushort* src = ok[i] ? (inp + goff[i]) : zp;
                v[i] = *(const uint4*)src;
            }
#pragma unroll
            for (int i = 0; i < 11; i++) {
                if (i * 128 + t < 1360) *(uint4*)(smem + (size_t)slot[i] * 8) = v[i];
            }
        }
        __syncthreads();

        const ushort* wbp = wB + ((size_t)ch * 18 * 64 + lane) * 8;
#pragma unroll
        for (int half = 0; half < 2; half++) {
            short8 bf[9];
#pragma unroll
            for (int j = 0; j < 9; j++)
                bf[j] = *(const short8*)(wbp + (size_t)(2 * j + half) * 512);
            const int cbr = half * 2 + lhalf;
#pragma unroll
            for (int kw = 0; kw < 3; kw++) {
                const int ww = lco + kw;
                const int cbs = cbr ^ (ww & 3) ^ ((ww >> 2) & 3);
                short8 a[6];
#pragma unroll
                for (int r = 0; r < 6; r++)
                    a[r] = *(const short8*)(smem + (size_t)((wid * 4 + r) * 136 + (ww << 2) + cbs) * 8);
#pragma unroll
                for (int q = 0; q < 4; q++)
#pragma unroll
                    for (int kh = 0; kh < 3; kh++)
                        acc[q] = __builtin_amdgcn_mfma_f32_32x32x16_bf16(
                            a[q + kh], bf[kh * 3 + kw], acc[q], 0, 0, 0);
            }
        }
    }

    if (EPI == 0) {
        // direct stores: per r the wave writes two contiguous 64B runs
#pragma unroll
        for (int q = 0; q < 4; q++) {
            size_t base = ((size_t)b * HW_ + (size_t)(h0 + wid * 4 + q) * W_ + w0) * 32;
#pragma unroll
            for (int r = 0; r < 16; r++) {
                int wl = (r & 3) + 8 * (r >> 2) + 4 * lhalf;
                float v0 = acc[q][r];
                if (RELU) v0 = fmaxf(v0, 0.f);
                outp[base + (size_t)wl * 32 + lco] = f2bf(v0);
            }
        }
    } else {
        __syncthreads();  // smem free for epilogue tile [pix 256][stride 40]
#pragma unroll
        for (int q = 0; q < 4; q++)
#pragma unroll
            for (int r = 0; r < 16; r++) {
                int wl = (r & 3) + 8 * (r >> 2) + 4 * lhalf;
                float v0 = acc[q][r];
                if (RELU) v0 = fmaxf(v0, 0.f);
                smem[(size_t)((wid * 4 + q) * 32 + wl) * 40 + lco] = f2bf(v0);
            }
        __syncthreads();
#pragma unroll
        for (int pi = 0; pi < 2; pi++) {
            int pp = pi * 128 + t;
            int hl = pp >> 5, wl = pp & 31;
            const ushort* tp = smem + (size_t)pp * 40;
            if (EPI == 1) {
                float xin[16];
                uint4 q0 = *(const uint4*)tp;
                uint4 q1 = *(const uint4*)(tp + 8);
                const ushort* u0 = (const ushort*)&q0;
                const ushort* u1 = (const ushort*)&q1;
#pragma unroll
                for (int j = 0; j < 8; j++) { xin[j] = bf2f(u0[j]); xin[8 + j] = bf2f(u1[j]); }
                size_t pix = (size_t)b * HW_ + (size_t)(h0 + hl) * W_ + w0 + wl;
#pragma unroll
                for (int g = 0; g < 4; g++) {
                    float accs = aux_b[g];
#pragma unroll
                    for (int ci = 0; ci < 16; ci++) accs = fmaf(xin[ci], aux_w[g * 16 + ci], accs);
                    outp[(size_t)g * 8 * HW_ + pix] = f2bf(sigmoidf_(accs));
                }
            } else {
                float accs = 0.f;
#pragma unroll
                for (int qq = 0; qq < 4; qq++) {
                    uint4 qv = *(const uint4*)(tp + qq * 8);
                    const ushort* uq = (const ushort*)&qv;
#pragma unroll
                    for (int j = 0; j < 8; j++) accs = fmaf(bf2f(uq[j]), aux_w[qq * 8 + j], accs);
                }
                float* fo = (float*)outp;
                fo[(size_t)b * HW_ + (size_t)(h0 + hl) * W_ + w0 + wl] = sigmoidf_(accs);
            }
        }
    }
}

// ============ dual conv: one staging of xh -> feat (w_in) + a1 (aw1, relu) ====
// 256 threads, 2 tiles/wave per output (R7-proven shape), direct stores.
__global__ __launch_bounds__(256, 4) void conv_dual(
    const ushort* __restrict__ in0, const ushort* __restrict__ wBa,
    const ushort* __restrict__ wBb, const ushort* __restrict__ zp,
    ushort* __restrict__ outA, ushort* __restrict__ outB) {
    __shared__ __align__(16) ushort smem[1360 * 8];
    const int t = threadIdx.x;
    const int wid = t >> 6;
    const int lane = t & 63;
    const int lco = lane & 31, lhalf = lane >> 5;
    const int w0 = blockIdx.x * 32, h0 = blockIdx.y * 8, b = blockIdx.z;

    uint goff[6];
    int slot[6];
    bool ok[6];
#pragma unroll
    for (int i = 0; i < 6; i++) {
        int u = i * 256 + t;
        int row = u / 136;
        int rem = u - row * 136;
        int p = rem >> 2, cb = rem & 3;
        int gh = h0 - 1 + row, gw = w0 - 1 + p;
        ok[i] = (u < 1360) && ((unsigned)gh < 256u) && ((unsigned)gw < 256u);
        goff[i] = ok[i] ? (((uint)b * HW_ + (uint)gh * W_ + (uint)gw) * 32 + cb * 8) : 0u;
        slot[i] = row * 136 + (p << 2) + (cb ^ (p & 3) ^ ((p >> 2) & 3));
    }

    floatx16 accA0, accA1, accB0, accB1;
#pragma unroll
    for (int i = 0; i < 16; i++) { accA0[i] = 0.f; accA1[i] = 0.f; accB0[i] = 0.f; accB1[i] = 0.f; }

    {
        uint4 v[6];
#pragma unroll
        for (int i = 0; i < 6; i++) {
            const ushort* src = ok[i] ? (in0 + goff[i]) : zp;
            v[i] = *(const uint4*)src;
        }
#pragma unroll
        for (int i = 0; i < 6; i++) {
            if (i * 256 + t < 1360) *(uint4*)(smem + (size_t)slot[i] * 8) = v[i];
        }
    }
    __syncthreads();

#pragma unroll
    for (int which = 0; which < 2; which++) {
        const ushort* wbp = (which ? wBb : wBa) + (size_t)lane * 8;
        floatx16& c0 = which ? accB0 : accA0;
        floatx16& c1 = which ? accB1 : accA1;
#pragma unroll
        for (int half = 0; half < 2; half++) {
            short8 bf[9];
#pragma unroll
            for (int j = 0; j < 9; j++)
                bf[j] = *(const short8*)(wbp + (size_t)(2 * j + half) * 512);
            const int cbr = half * 2 + lhalf;
#pragma unroll
            for (int kw = 0; kw < 3; kw++) {
                const int ww = lco + kw;
                const int cbs = cbr ^ (ww & 3) ^ ((ww >> 2) & 3);
                short8 a[4];
#pragma unroll
                for (int r = 0; r < 4; r++)
                    a[r] = *(const short8*)(smem + (size_t)((wid * 2 + r) * 136 + (ww << 2) + cbs) * 8);
#pragma unroll
                for (int kh = 0; kh < 3; kh++) {
                    c0 = __builtin_amdgcn_mfma_f32_32x32x16_bf16(a[kh], bf[kh * 3 + kw], c0, 0, 0, 0);
                    c1 = __builtin_amdgcn_mfma_f32_32x32x16_bf16(a[kh + 1], bf[kh * 3 + kw], c1, 0, 0, 0);
                }
            }
        }
    }

#pragma unroll
    for (int r = 0; r < 16; r++) {
        int wl = (r & 3) + 8 * (r >> 2) + 4 * lhalf;
        size_t p0 = (((size_t)b * HW_ + (h0 + wid * 2) * W_ + w0 + wl) * 32) + lco;
        outA[p0] = f2bf(accA0[r]);
        outA[p0 + (size_t)W_ * 32] = f2bf(accA1[r]);
        outB[p0] = f2bf(fmaxf(accB0[r], 0.f));
        outB[p0 + (size_t)W_ * 32] = f2bf(fmaxf(accB1[r], 0.f));
    }
}

// ============ segmented IRNN scan, vectorized 8ch/thread, both dirs ============
template<int VERT>
__global__ __launch_bounds__(256) void scan_seg(
    const ushort* __restrict__ feat, const float* __restrict__ alpha,
    const ushort* __restrict__ wmapT, ushort* __restrict__ gfwd,
    ushort* __restrict__ gbwd, int gf, int gb) {
    const int t = threadIdx.x;
    const int cg = t & 3;
    const int bx = blockIdx.x;
    const int col = (bx & 3) * 64 + (t >> 2);
    const int seg = (bx >> 2) & 7;
    const int dir = (bx >> 5) & 1;
    const int b = bx >> 6;
    const int c0 = cg * 8;

    float a[8];
#pragma unroll
    for (int j = 0; j < 8; j++) a[j] = alpha[c0 + j];

    const ushort* wplane = wmapT + (size_t)(dir ? gb : gf) * 8 * HW_ + (size_t)b * HW_;
    ushort* gout = dir ? gbwd : gfwd;

    const int main0 = seg * 32;
    const int start = (seg == 0) ? 0 : main0 - 16;
    const int cnt = main0 - start + 32;

    auto pixof = [&](int p) -> size_t {
        int phys = dir ? 255 - p : p;
        return VERT ? ((size_t)phys * W_ + col) : ((size_t)col * W_ + phys);
    };

    uint4 xv[4];
    ushort wv[4];
#pragma unroll
    for (int k = 0; k < 4; k++) {
        size_t pix = pixof(start + k);
        xv[k] = *(const uint4*)(feat + ((size_t)b * HW_ + pix) * 32 + c0);
        wv[k] = wplane[pix];
    }
    float prev[8];
#pragma unroll
    for (int j = 0; j < 8; j++) prev[j] = 0.f;

    for (int i = 0; i < cnt; i += 4) {
#pragma unroll
        for (int k = 0; k < 4; k++) {
            const int p = start + i + k;
            uint4 xcur = xv[k];
            ushort wcur = wv[k];
            if (i + k + 4 < cnt) {
                size_t pix = pixof(p + 4);
                xv[k] = *(const uint4*)(feat + ((size_t)b * HW_ + pix) * 32 + c0);
                wv[k] = wplane[pix];
            }
            const ushort* xu = (const ushort*)&xcur;
            if (p >= main0) {
                float wmv = bf2f(wcur);
                ushort o[8];
#pragma unroll
                for (int j = 0; j < 8; j++) {
                    float cur = fmaxf(fmaf(a[j], prev[j], bf2f(xu[j])), 0.f);
                    prev[j] = cur;
                    o[j] = f2bf(cur * wmv);
                }
                *(uint4*)(gout + ((size_t)b * HW_ + pixof(p)) * 32 + c0) = *(const uint4*)o;
            } else {
#pragma unroll
                for (int j = 0; j < 8; j++)
                    prev[j] = fmaxf(fmaf(a[j], prev[j], bf2f(xu[j])), 0.f);
            }
        }
    }
}

extern "C" void kernel_launch(void* const* d_in, const int* in_sizes, int n_in,
                              void* d_out, int out_size, void* d_ws, size_t ws_size,
                              hipStream_t stream) {
    const float* x      = (const float*)d_in[0];
    const float* alpha1 = (const float*)d_in[1];
    const float* alpha2 = (const float*)d_in[2];
    const float* w_in   = (const float*)d_in[3];
    const float* w2     = (const float*)d_in[4];
    const float* w3     = (const float*)d_in[5];
    const float* aw1    = (const float*)d_in[6];
    const float* aw2    = (const float*)d_in[7];
    const float* aw3    = (const float*)d_in[8];
    const float* ab3    = (const float*)d_in[9];
    const float* wout   = (const float*)d_in[10];
    float* out = (float*)d_out;

    // ---- workspace carve (ushorts), ~206 MB ----
    const size_t TEN = (size_t)8 * HW_ * 32;
    ushort* p = (ushort*)d_ws;
    ushort* xh    = p; p += TEN;
    ushort* feat  = p; p += TEN;
    ushort* g0    = p; p += TEN;
    ushort* g1    = p; p += TEN;
    ushort* g2    = p; p += TEN;
    ushort* g3    = p; p += TEN;
    ushort* wmapT = p; p += (size_t)4 * 8 * HW_;
    ushort* w_inB = p; p += 9216;
    ushort* w2B   = p; p += 36864;
    ushort* w3B   = p; p += 36864;
    ushort* aw1B  = p; p += 9216;
    ushort* aw2B  = p; p += 9216;
    ushort* zp    = p; p += 64;
    ushort* a1z   = g1;  // attention intermediate overlays g1 (dead until scans)

    prep_weights<<<396, 256, 0, stream>>>(w_in, w2, w3, aw1, aw2,
                                          w_inB, w2B, w3B, aw1B, aw2B, zp);
    transform_x<<<dim3(4, 256, 8), 256, 0, stream>>>(x, xh);

    dim3 gconv(8, 32, 8);

    // trunk conv + first attention conv share one staging pass of xh
    conv_dual<<<gconv, 256, 0, stream>>>(xh, w_inB, aw1B, zp, feat, a1z);
    // second attention conv with fused att1x1+sigmoid -> wmapT planes
    conv_mfma<1, 1, true><<<gconv, 128, 0, stream>>>(a1z, a1z, a1z, a1z, aw2B, zp,
                                                     wmapT, aw3, ab3);

    // round 1 scans: g0=td, g1=lr, g2=dt, g3=rl
    scan_seg<1><<<512, 256, 0, stream>>>(feat, alpha1, wmapT, g0, g2, 0, 2);
    scan_seg<0><<<512, 256, 0, stream>>>(feat, alpha1, wmapT, g1, g3, 1, 3);

    conv_mfma<4, 0, false><<<gconv, 128, 0, stream>>>(g0, g1, g2, g3, w2B, zp,
                                                      feat, nullptr, nullptr);

    // round 2 scans
    scan_seg<1><<<512, 256, 0, stream>>>(feat, alpha2, wmapT, g0, g2, 0, 2);
    scan_seg<0><<<512, 256, 0, stream>>>(feat, alpha2, wmapT, g1, g3, 1, 3);

    // final conv with fused out1x1+sigmoid -> fp32 out
    conv_mfma<4, 2, true><<<gconv, 128, 0, stream>>>(g0, g1, g2, g3, w3B, zp,
                                                     (ushort*)out, wout, nullptr);
}

// Round 11
// 375.762 us; speedup vs baseline: 1.3865x; 1.3865x over previous
//
#include <hip/hip_runtime.h>
#include <cstddef>

#define H_ 256
#define W_ 256
#define HW_ 65536

typedef unsigned int uint;
typedef unsigned short ushort;
typedef __attribute__((ext_vector_type(8))) short short8;
typedef __attribute__((ext_vector_type(16))) float floatx16;

__device__ __forceinline__ float bf2f(ushort u) {
    return __uint_as_float(((uint)u) << 16);
}
__device__ __forceinline__ ushort f2bf(float f) {
    uint u = __float_as_uint(f);
    uint r = (u + 0x7fffu + ((u >> 16) & 1u)) >> 16;
    return (ushort)r;
}
__device__ __forceinline__ float sigmoidf_(float x) {
    return 1.0f / (1.0f + expf(-x));
}

// ============ weight prep: OIHW fp32 -> MFMA-fragment-ordered bf16 ============
__device__ __forceinline__ void prep_one(const float* src, ushort* dst,
                                         int CO, int CI, int e) {
    int chunk = e / 9216;
    int r = e - chunk * 9216;
    int co = r / 288;
    int kk = r - co * 288;
    int khw = kk >> 5;
    int ci = kk & 31;
    int cig = chunk * 32 + ci;
    float v = 0.f;
    if (co < CO && cig < CI) v = src[(co * CI + cig) * 9 + khw];
    int s = kk >> 4;
    int lane = ((kk >> 3) & 1) * 32 + co;
    int j = kk & 7;
    dst[(((size_t)chunk * 18 + s) * 64 + lane) * 8 + j] = f2bf(v);
}

__global__ __launch_bounds__(256) void prep_weights(
    const float* __restrict__ w_in, const float* __restrict__ w2,
    const float* __restrict__ w3, const float* __restrict__ aw1,
    const float* __restrict__ aw2,
    ushort* __restrict__ w_inB, ushort* __restrict__ w2B,
    ushort* __restrict__ w3B, ushort* __restrict__ aw1B,
    ushort* __restrict__ aw2B, ushort* __restrict__ zp) {
    int idx = blockIdx.x * 256 + threadIdx.x;
    if (idx < 64) zp[idx] = 0;
    if (idx < 9216)        prep_one(w_in, w_inB, 32, 32, idx);
    else if (idx < 46080)  prep_one(w2, w2B, 32, 128, idx - 9216);
    else if (idx < 82944)  prep_one(w3, w3B, 32, 128, idx - 46080);
    else if (idx < 92160)  prep_one(aw1, aw1B, 16, 32, idx - 82944);
    else if (idx < 101376) prep_one(aw2, aw2B, 16, 16, idx - 92160);
}

// ============ x: NCHW fp32 -> NHWC bf16 (32 ch) ============
__global__ __launch_bounds__(256) void transform_x(const float* __restrict__ x,
                                                   ushort* __restrict__ xh) {
    __shared__ float s[64][33];
    const int t = threadIdx.x;
    const int w0 = blockIdx.x * 64, h = blockIdx.y, b = blockIdx.z;
    {
        int ww = t & 63, c0 = (t >> 6) * 8;
#pragma unroll
        for (int j = 0; j < 8; j++) {
            int c = c0 + j;
            s[ww][c] = x[((size_t)(b * 32 + c)) * HW_ + h * W_ + w0 + ww];
        }
    }
    __syncthreads();
    {
        int p = t >> 2, cb = t & 3;
        ushort tmp[8];
#pragma unroll
        for (int j = 0; j < 8; j++) tmp[j] = f2bf(s[p][cb * 8 + j]);
        *(uint4*)(xh + (((size_t)b * HW_ + h * W_ + w0 + p) * 32) + cb * 8) =
            *(const uint4*)tmp;
    }
}

// ---- shared staging-descriptor setup (32x8 tile, 10x34 halo, XOR swizzle) ----
struct StageDesc {
    uint goff[6];
    int slot[6];
    bool ok[6];
};
__device__ __forceinline__ void make_desc(StageDesc& d, int t, int w0, int h0, int b) {
#pragma unroll
    for (int i = 0; i < 6; i++) {
        int u = i * 256 + t;
        int row = u / 136;
        int rem = u - row * 136;
        int p = rem >> 2, cb = rem & 3;
        int gh = h0 - 1 + row, gw = w0 - 1 + p;
        d.ok[i] = (u < 1360) && ((unsigned)gh < 256u) && ((unsigned)gw < 256u);
        d.goff[i] = d.ok[i] ? (((uint)b * HW_ + (uint)gh * W_ + (uint)gw) * 32 + cb * 8) : 0u;
        d.slot[i] = row * 136 + (p << 2) + (cb ^ (p & 3) ^ ((p >> 2) & 3));
    }
}
// load + immediate LDS write (R7 structure: no cross-phase register carry)
__device__ __forceinline__ void stage6(ushort* smem, const StageDesc& d,
                                       const ushort* __restrict__ inp,
                                       const ushort* __restrict__ zp, int t) {
    uint4 v[6];
#pragma unroll
    for (int i = 0; i < 6; i++) {
        const ushort* src = d.ok[i] ? (inp + d.goff[i]) : zp;
        v[i] = *(const uint4*)src;
    }
#pragma unroll
    for (int i = 0; i < 6; i++) {
        if (i * 256 + t < 1360) *(uint4*)(smem + (size_t)d.slot[i] * 8) = v[i];
    }
}
// MFMA phase over one staged chunk (36 MFMAs/wave into acc0/acc1)
__device__ __forceinline__ void mfma_chunk(const ushort* smem, const ushort* wbp,
                                           int lco, int lhalf, int wid,
                                           floatx16& acc0, floatx16& acc1) {
#pragma unroll
    for (int half = 0; half < 2; half++) {
        short8 bf[9];
#pragma unroll
        for (int j = 0; j < 9; j++)
            bf[j] = *(const short8*)(wbp + (size_t)(2 * j + half) * 512);
        const int cbr = half * 2 + lhalf;
#pragma unroll
        for (int kw = 0; kw < 3; kw++) {
            const int ww = lco + kw;
            const int cbs = cbr ^ (ww & 3) ^ ((ww >> 2) & 3);
            short8 a[4];
#pragma unroll
            for (int r = 0; r < 4; r++)
                a[r] = *(const short8*)(smem + (size_t)((wid * 2 + r) * 136 + (ww << 2) + cbs) * 8);
#pragma unroll
            for (int kh = 0; kh < 3; kh++) {
                acc0 = __builtin_amdgcn_mfma_f32_32x32x16_bf16(a[kh], bf[kh * 3 + kw], acc0, 0, 0, 0);
                acc1 = __builtin_amdgcn_mfma_f32_32x32x16_bf16(a[kh + 1], bf[kh * 3 + kw], acc1, 0, 0, 0);
            }
        }
    }
}

// ============ unified conv 3x3 (implicit GEMM, MFMA 32x32x16) =================
// EPI=0: direct bf16 NHWC stores (R7-measured 52us). EPI=1: fused att1x1
// (16ch dot -> 4 sigmoid planes). EPI=2: fused out1x1 (-> fp32 sigmoid out).
template<int NCHUNK, int EPI, bool RELU>
__global__ __launch_bounds__(256, 4) void conv_mfma(
    const ushort* __restrict__ in0, const ushort* __restrict__ in1,
    const ushort* __restrict__ in2, const ushort* __restrict__ in3,
    const ushort* __restrict__ wB, const ushort* __restrict__ zp,
    ushort* __restrict__ outp, const float* __restrict__ aux_w,
    const float* __restrict__ aux_b) {
    __shared__ __align__(16) ushort smem[1360 * 8];  // 21.25 KB
    const int t = threadIdx.x;
    const int wid = t >> 6;
    const int lane = t & 63;
    const int lco = lane & 31, lhalf = lane >> 5;
    const int w0 = blockIdx.x * 32, h0 = blockIdx.y * 8, b = blockIdx.z;
    const ushort* ins[4] = {in0, in1, in2, in3};

    StageDesc d;
    make_desc(d, t, w0, h0, b);

    floatx16 acc0, acc1;
#pragma unroll
    for (int i = 0; i < 16; i++) { acc0[i] = 0.f; acc1[i] = 0.f; }

#pragma unroll
    for (int ch = 0; ch < NCHUNK; ch++) {
        __syncthreads();
        stage6(smem, d, ins[ch], zp, t);
        __syncthreads();
        mfma_chunk(smem, wB + ((size_t)ch * 18 * 64 + lane) * 8, lco, lhalf, wid,
                   acc0, acc1);
    }

    if (EPI == 0) {
        // direct stores: per r the wave writes two contiguous 64B runs
#pragma unroll
        for (int r = 0; r < 16; r++) {
            int wl = (r & 3) + 8 * (r >> 2) + 4 * lhalf;
            float v0 = acc0[r], v1 = acc1[r];
            if (RELU) { v0 = fmaxf(v0, 0.f); v1 = fmaxf(v1, 0.f); }
            size_t p0 = (((size_t)b * HW_ + (h0 + wid * 2) * W_ + w0 + wl) * 32) + lco;
            outp[p0] = f2bf(v0);
            outp[p0 + (size_t)W_ * 32] = f2bf(v1);
        }
    } else {
        __syncthreads();  // smem free for epilogue tile [pix 256][stride 40]
#pragma unroll
        for (int r = 0; r < 16; r++) {
            int wl = (r & 3) + 8 * (r >> 2) + 4 * lhalf;
            float v0 = acc0[r], v1 = acc1[r];
            if (RELU) { v0 = fmaxf(v0, 0.f); v1 = fmaxf(v1, 0.f); }
            int pix0 = (wid * 2) * 32 + wl;
            smem[(size_t)pix0 * 40 + lco] = f2bf(v0);
            smem[(size_t)(pix0 + 32) * 40 + lco] = f2bf(v1);
        }
        __syncthreads();
        const ushort* tp = smem + (size_t)t * 40;
        if (EPI == 1) {
            float xin[16];
            uint4 q0 = *(const uint4*)tp;
            uint4 q1 = *(const uint4*)(tp + 8);
            const ushort* u0 = (const ushort*)&q0;
            const ushort* u1 = (const ushort*)&q1;
#pragma unroll
            for (int j = 0; j < 8; j++) { xin[j] = bf2f(u0[j]); xin[8 + j] = bf2f(u1[j]); }
            size_t pix = (size_t)b * HW_ + (size_t)(h0 + (t >> 5)) * W_ + w0 + (t & 31);
#pragma unroll
            for (int g = 0; g < 4; g++) {
                float acc = aux_b[g];
#pragma unroll
                for (int ci = 0; ci < 16; ci++) acc = fmaf(xin[ci], aux_w[g * 16 + ci], acc);
                outp[(size_t)g * 8 * HW_ + pix] = f2bf(sigmoidf_(acc));
            }
        } else {
            float acc = 0.f;
#pragma unroll
            for (int q = 0; q < 4; q++) {
                uint4 qv = *(const uint4*)(tp + q * 8);
                const ushort* uq = (const ushort*)&qv;
#pragma unroll
                for (int j = 0; j < 8; j++) acc = fmaf(bf2f(uq[j]), aux_w[q * 8 + j], acc);
            }
            float* fo = (float*)outp;
            fo[(size_t)b * HW_ + (size_t)(h0 + (t >> 5)) * W_ + w0 + (t & 31)] = sigmoidf_(acc);
        }
    }
}

// ============ dual conv: one staging of xh -> feat (w_in) + a1 (aw1, relu) ====
__global__ __launch_bounds__(256, 4) void conv_dual(
    const ushort* __restrict__ in0, const ushort* __restrict__ wBa,
    const ushort* __restrict__ wBb, const ushort* __restrict__ zp,
    ushort* __restrict__ outA, ushort* __restrict__ outB) {
    __shared__ __align__(16) ushort smem[1360 * 8];
    const int t = threadIdx.x;
    const int wid = t >> 6;
    const int lane = t & 63;
    const int lco = lane & 31, lhalf = lane >> 5;
    const int w0 = blockIdx.x * 32, h0 = blockIdx.y * 8, b = blockIdx.z;

    StageDesc d;
    make_desc(d, t, w0, h0, b);

    floatx16 accA0, accA1, accB0, accB1;
#pragma unroll
    for (int i = 0; i < 16; i++) { accA0[i] = 0.f; accA1[i] = 0.f; accB0[i] = 0.f; accB1[i] = 0.f; }

    stage6(smem, d, in0, zp, t);
    __syncthreads();
    mfma_chunk(smem, wBa + (size_t)lane * 8, lco, lhalf, wid, accA0, accA1);
    mfma_chunk(smem, wBb + (size_t)lane * 8, lco, lhalf, wid, accB0, accB1);

#pragma unroll
    for (int r = 0; r < 16; r++) {
        int wl = (r & 3) + 8 * (r >> 2) + 4 * lhalf;
        size_t p0 = (((size_t)b * HW_ + (h0 + wid * 2) * W_ + w0 + wl) * 32) + lco;
        outA[p0] = f2bf(accA0[r]);
        outA[p0 + (size_t)W_ * 32] = f2bf(accA1[r]);
        outB[p0] = f2bf(fmaxf(accB0[r], 0.f));
        outB[p0 + (size_t)W_ * 32] = f2bf(fmaxf(accB1[r], 0.f));
    }
}

// ============ segmented IRNN scan, vectorized 8ch/thread ============
// One dispatch covers BOTH axes (axis = blockIdx bit, wave-uniform).
// 8 segments of 32 + 16-step warmup (alpha<=0.2 -> 0.2^16 ~ 5e-12).
template<int VERT>
__device__ __forceinline__ void scan_body(
    const ushort* __restrict__ feat, const float* __restrict__ alpha,
    const ushort* __restrict__ wmapT, ushort* __restrict__ gfwd,
    ushort* __restrict__ gbwd, int gf, int gb, int bx, int t) {
    const int cg = t & 3;
    const int col = (bx & 3) * 64 + (t >> 2);
    const int seg = (bx >> 2) & 7;
    const int dir = (bx >> 5) & 1;
    const int b = bx >> 6;
    const int c0 = cg * 8;

    float a[8];
#pragma unroll
    for (int j = 0; j < 8; j++) a[j] = alpha[c0 + j];

    const ushort* wplane = wmapT + (size_t)(dir ? gb : gf) * 8 * HW_ + (size_t)b * HW_;
    ushort* gout = dir ? gbwd : gfwd;

    const int main0 = seg * 32;
    const int start = (seg == 0) ? 0 : main0 - 16;
    const int cnt = main0 - start + 32;

    auto pixof = [&](int p) -> size_t {
        int phys = dir ? 255 - p : p;
        return VERT ? ((size_t)phys * W_ + col) : ((size_t)col * W_ + phys);
    };

    uint4 xv[4];
    ushort wv[4];
#pragma unroll
    for (int k = 0; k < 4; k++) {
        size_t pix = pixof(start + k);
        xv[k] = *(const uint4*)(feat + ((size_t)b * HW_ + pix) * 32 + c0);
        wv[k] = wplane[pix];
    }
    float prev[8];
#pragma unroll
    for (int j = 0; j < 8; j++) prev[j] = 0.f;

    for (int i = 0; i < cnt; i += 4) {
#pragma unroll
        for (int k = 0; k < 4; k++) {
            const int p = start + i + k;
            uint4 xcur = xv[k];
            ushort wcur = wv[k];
            if (i + k + 4 < cnt) {
                size_t pix = pixof(p + 4);
                xv[k] = *(const uint4*)(feat + ((size_t)b * HW_ + pix) * 32 + c0);
                wv[k] = wplane[pix];
            }
            const ushort* xu = (const ushort*)&xcur;
            if (p >= main0) {
                float wmv = bf2f(wcur);
                ushort o[8];
#pragma unroll
                for (int j = 0; j < 8; j++) {
                    float cur = fmaxf(fmaf(a[j], prev[j], bf2f(xu[j])), 0.f);
                    prev[j] = cur;
                    o[j] = f2bf(cur * wmv);
                }
                *(uint4*)(gout + ((size_t)b * HW_ + pixof(p)) * 32 + c0) = *(const uint4*)o;
            } else {
#pragma unroll
                for (int j = 0; j < 8; j++)
                    prev[j] = fmaxf(fmaf(a[j], prev[j], bf2f(xu[j])), 0.f);
            }
        }
    }
}

__global__ __launch_bounds__(256) void scan_both(
    const ushort* __restrict__ feat, const float* __restrict__ alpha,
    const ushort* __restrict__ wmapT, ushort* __restrict__ g0,
    ushort* __restrict__ g1, ushort* __restrict__ g2, ushort* __restrict__ g3) {
    const int bx = blockIdx.x & 511;
    if (blockIdx.x < 512)
        scan_body<1>(feat, alpha, wmapT, g0, g2, 0, 2, bx, threadIdx.x);
    else
        scan_body<0>(feat, alpha, wmapT, g1, g3, 1, 3, bx, threadIdx.x);
}

extern "C" void kernel_launch(void* const* d_in, const int* in_sizes, int n_in,
                              void* d_out, int out_size, void* d_ws, size_t ws_size,
                              hipStream_t stream) {
    const float* x      = (const float*)d_in[0];
    const float* alpha1 = (const float*)d_in[1];
    const float* alpha2 = (const float*)d_in[2];
    const float* w_in   = (const float*)d_in[3];
    const float* w2     = (const float*)d_in[4];
    const float* w3     = (const float*)d_in[5];
    const float* aw1    = (const float*)d_in[6];
    const float* aw2    = (const float*)d_in[7];
    const float* aw3    = (const float*)d_in[8];
    const float* ab3    = (const float*)d_in[9];
    const float* wout   = (const float*)d_in[10];
    float* out = (float*)d_out;

    // ---- workspace carve (ushorts), ~206 MB ----
    const size_t TEN = (size_t)8 * HW_ * 32;
    ushort* p = (ushort*)d_ws;
    ushort* xh    = p; p += TEN;
    ushort* feat  = p; p += TEN;
    ushort* g0    = p; p += TEN;
    ushort* g1    = p; p += TEN;
    ushort* g2    = p; p += TEN;
    ushort* g3    = p; p += TEN;
    ushort* wmapT = p; p += (size_t)4 * 8 * HW_;
    ushort* w_inB = p; p += 9216;
    ushort* w2B   = p; p += 36864;
    ushort* w3B   = p; p += 36864;
    ushort* aw1B  = p; p += 9216;
    ushort* aw2B  = p; p += 9216;
    ushort* zp    = p; p += 64;
    ushort* a1z   = g1;  // attention intermediate overlays g1 (dead until scans)

    prep_weights<<<396, 256, 0, stream>>>(w_in, w2, w3, aw1, aw2,
                                          w_inB, w2B, w3B, aw1B, aw2B, zp);
    transform_x<<<dim3(4, 256, 8), 256, 0, stream>>>(x, xh);

    dim3 gconv(8, 32, 8);

    // trunk conv + first attention conv share one staging pass of xh
    conv_dual<<<gconv, 256, 0, stream>>>(xh, w_inB, aw1B, zp, feat, a1z);
    // second attention conv with fused att1x1+sigmoid -> wmapT planes
    conv_mfma<1, 1, true><<<gconv, 256, 0, stream>>>(a1z, a1z, a1z, a1z, aw2B, zp,
                                                     wmapT, aw3, ab3);

    // round 1 scans (both axes, one dispatch): g0=td, g1=lr, g2=dt, g3=rl
    scan_both<<<1024, 256, 0, stream>>>(feat, alpha1, wmapT, g0, g1, g2, g3);

    conv_mfma<4, 0, false><<<gconv, 256, 0, stream>>>(g0, g1, g2, g3, w2B, zp,
                                                      feat, nullptr, nullptr);

    // round 2 scans
    scan_both<<<1024, 256, 0, stream>>>(feat, alpha2, wmapT, g0, g1, g2, g3);

    // final conv with fused out1x1+sigmoid -> fp32 out
    conv_mfma<4, 2, true><<<gconv, 256, 0, stream>>>(g0, g1, g2, g3, w3B, zp,
                                                     (ushort*)out, wout, nullptr);
}